// Round 5
// baseline (457.554 us; speedup 1.0000x reference)
//
#include <hip/hip_runtime.h>

namespace {
constexpr int Bn = 2, Dn = 48, Hn = 320, Wn = 640;
constexpr int R = 2, K = 5, K2 = 25, C3 = 75;
constexpr int TW = 64, TH = 4;
constexpr int LW = TW + 2 * R;   // 68 staged cols
constexpr int NT = TW * TH;      // 256 threads
constexpr int LTOT = 544;        // 8 rows * 68 cols useful spatial
constexpr int SPAD = 640;        // padded spatial/slot -> 1280 dwords = 5 DMAs/wave, uniform
constexpr int NSLOT = 6;         // pair-slots: 6 * 5120 B = 30.7 KB LDS
}

// out[b,d,h,w] = sum_{ij in 5x5} w0*x[d] + w1*x[d-1] + w2*x[d+1], zero-padded.
// Sg(p) = sum_ij wg[ij]*win_p[ij]; out[d] = S0(d)+S1(d-1)+S2(d+1).
//
// r5: PLANE-PAIR LDS. Slot s holds float2{x[2P][s], x[2P+1][s]} for 640
// padded spatial positions. One aligned ds_read_b64 feeds 6 FMAs (3 weight
// groups x 2 planes): 25 b64 per 2 planes vs 50 b32 -> halves the CU-shared
// LDS-pipe issue (was ~72 us/pass, the dominant floor; now ~40).
//
// The interleave is built BY THE DMA: LDS dest is linear (wave-uniform base
// + lane*4), global src is PER-LANE (m173): parity lane&1 picks the plane,
// lane>>1 picks spatial. 5 DMAs/wave/pair-step, uniform across waves.
//
// vmcnt accounting (per-wave, in-issue-order retirement; 5 loads + 2 stores
// per step): at barrier-P need pair-P's DMAs retired. Newer ops:
//   P=0: pairs 1,2 (prologue)                          -> 10
//   P=1: dma(2)5 + [dma(3)5 + st(2)]                   -> 12
//   P=2: dma(3)5+st2+dma(4)5+st2                       -> 14
//   P>=3 steady: st2+dma5+st2+dma5+st2                 -> 16
//   P=22: st2+dma(23)5+st2+st2                         -> 11
//   P=23: st2+st2+st2                                  -> 6
// Dummy first store (own out[47], overwritten by the final store) keeps the
// store count uniform at 2/step.
//
// LAUNCH BOUNDS: (256,2) and nothing tighter — (256,4) capped VGPR at 64,
// spilled wr[75], 13x traffic (round-1 disaster). Register budget binds.
#define BARRIER(N) \
    asm volatile("s_waitcnt vmcnt(" #N ") lgkmcnt(0)\n\ts_barrier" ::: "memory")

__global__ __launch_bounds__(NT, 2)
void lga_pass(const float* __restrict__ x, const float* __restrict__ wt,
              float* __restrict__ out) {
    __shared__ float2 pl2[NSLOT][SPAD];   // 30720 B

    const int tx = threadIdx.x;          // 0..63 (w); one wave per ty row
    const int ty = threadIdx.y;          // 0..3  (h)

    const int w0pix = blockIdx.x * TW;
    const int h0pix = blockIdx.y * TH;
    const int b = blockIdx.z;

    const int gw = w0pix + tx;
    const int gh = h0pix + ty;

    const size_t ps = (size_t)Hn * Wn;

    // ---- per-lane gather offsets for the pair-interleaved staging ----
    // instr t of wave ty covers slot dwords [ty*320 + t*64, +64):
    //   lane l -> dword ty*320+t*64+l: spatial s = ty*160+t*32+(l>>1), plane
    //   parity q = l&1. Clamped source for pad/halo-OOB (weight-zeroed).
    int soffA[5];
#pragma unroll
    for (int t = 0; t < 5; ++t) {
        int s = ty * 160 + t * 32 + (tx >> 1);
        int rr = s / LW;
        int cc = s - rr * LW;
        int hh = h0pix - R + rr;
        int ww = w0pix - R + cc;
        bool ok = (s < LTOT) && hh >= 0 && hh < Hn && ww >= 0 && ww < Wn;
        soffA[t] = ok ? (hh * Wn + ww) : 0;
    }

    const float* xb = x + (size_t)b * Dn * ps;
    const float* xq = xb + (size_t)(tx & 1) * ps;   // per-lane parity base

    // ---- 75 per-pixel guidance weights -> registers, off-image taps zeroed ----
    float wr[C3];
    {
        const float* wp = wt + (size_t)b * C3 * ps + (size_t)gh * Wn + gw;
#pragma unroll
        for (int c = 0; c < C3; ++c) wr[c] = wp[(size_t)c * ps];
#pragma unroll
        for (int i = 0; i < K; ++i) {
            const int hh = gh + i - R;
            const bool vh = (hh >= 0) && (hh < Hn);
#pragma unroll
            for (int j = 0; j < K; ++j) {
                const int ww = gw + j - R;
                if (!(vh && ww >= 0 && ww < Wn)) {
                    wr[i * K + j] = 0.f;
                    wr[K2 + i * K + j] = 0.f;
                    wr[2 * K2 + i * K + j] = 0.f;
                }
            }
        }
    }

    float* op = out + (size_t)b * Dn * ps + (size_t)gh * Wn + gw;
    const int lbase = ty * LW + tx;      // spatial window base (float2 index)

    // DMA one plane-pair (base = xq + 2P*ps) into slot: 5 uniform gathers.
    auto dma = [&](const float* pbase, int slot) {
#pragma unroll
        for (int t = 0; t < 5; ++t) {
            __builtin_amdgcn_global_load_lds(
                (const __attribute__((address_space(1))) void*)(pbase + soffA[t]),
                (__attribute__((address_space(3))) void*)(&pl2[slot][ty * 160 + t * 32]),
                4, 0, 0);
        }
    };

    float carry = 0.f, s1prev = 0.f;
    const float* pref = xq;              // next pair to issue

    // prologue: pairs 0,1,2 -> slots 0,1,2 (15 loads in flight)
    dma(pref, 0); pref += 2 * ps;
    dma(pref, 1); pref += 2 * ps;
    dma(pref, 2); pref += 2 * ps;

    // one pair-step: issue pair P+3, compute planes 2P,2P+1 from slot P%6,
    // store out[2P-1], out[2P] (dummy first store keeps counts uniform).
    auto stepc = [&](int slot, bool issue, bool first) {
        if (issue) { dma(pref, (slot + 3 >= NSLOT) ? slot - 3 : slot + 3); pref += 2 * ps; }
        float S0a = 0.f, S1a = 0.f, S2a = 0.f;
        float S0b = 0.f, S1b = 0.f, S2b = 0.f;
        const float2* wb = &pl2[slot][lbase];
#pragma unroll
        for (int i = 0; i < K; ++i)
#pragma unroll
            for (int j = 0; j < K; ++j) {
                float2 v = wb[i * LW + j];           // ds_read_b64, 8B-aligned
                float w0 = wr[i * K + j];
                float w1 = wr[K2 + i * K + j];
                float w2 = wr[2 * K2 + i * K + j];
                S0a += w0 * v.x; S1a += w1 * v.x; S2a += w2 * v.x;
                S0b += w0 * v.y; S1b += w1 * v.y; S2b += w2 * v.y;
            }
        if (first) op[(size_t)(Dn - 1) * ps] = carry + S2a;  // dummy; overwritten
        else       { *op = carry + S2a; op += ps; }
        carry = S0a + s1prev; s1prev = S1a;
        *op = carry + S2b; op += ps;
        carry = S0b + s1prev; s1prev = S1b;
    };

    BARRIER(10); stepc(0, true, true);    // P=0
    BARRIER(12); stepc(1, true, false);   // P=1
    BARRIER(14); stepc(2, true, false);   // P=2
    for (int g = 0; g < 3; ++g) {         // P=3..20 (all steady, all issue)
        BARRIER(16); stepc(3, true, false);
        BARRIER(16); stepc(4, true, false);
        BARRIER(16); stepc(5, true, false);
        BARRIER(16); stepc(0, true, false);
        BARRIER(16); stepc(1, true, false);
        BARRIER(16); stepc(2, true, false);
    }
    BARRIER(16); stepc(3, false, false);  // P=21
    BARRIER(11); stepc(4, false, false);  // P=22
    BARRIER(6);  stepc(5, false, false);  // P=23
    // out[D-1] = S0(D-1) + S1(D-2)  (S2 of plane D is zero); overwrites dummy
    *op = carry;
}

extern "C" void kernel_launch(void* const* d_in, const int* in_sizes, int n_in,
                              void* d_out, int out_size, void* d_ws, size_t ws_size,
                              hipStream_t stream) {
    const float* x = (const float*)d_in[0];
    const float* w = (const float*)d_in[1];
    // d_in[2] = radius (always 2 here; compile-time constant)
    float* out = (float*)d_out;
    float* tmp = (float*)d_ws;   // intermediate y (78.6 MB)

    dim3 block(TW, TH, 1);
    dim3 grid(Wn / TW, Hn / TH, Bn);

    lga_pass<<<grid, block, 0, stream>>>(x, w, tmp);
    lga_pass<<<grid, block, 0, stream>>>(tmp, w, out);
}

// Round 7
// 387.874 us; speedup vs baseline: 1.1796x; 1.1796x over previous
//
#include <hip/hip_runtime.h>

namespace {
constexpr int Bn = 2, Dn = 48, Hn = 320, Wn = 640;
constexpr int R = 2, K = 5, K2 = 25, C3 = 75;
constexpr int TW = 64, TH = 4;
constexpr int LW = TW + 2 * R;   // 68 floats per staged row
constexpr int LH = TH + 2 * R;   // 8 staged rows
constexpr int NT = TW * TH;      // 256 threads
constexpr int LTOT = LH * LW;    // 544 useful floats per plane slot
constexpr int LTOTP = 768;       // padded: 3 full 256-lane chunks (uniform DMA count)
constexpr int NSLOT = 12;        // LDS plane slots: 12 * 3072 B = 36.9 KB
}

// out[b,d,h,w] = sum_{ij in 5x5} w0*x[d] + w1*x[d-1] + w2*x[d+1], zero-padded.
// Sg(p) = sum_ij wg[ij]*win_p[ij]; out[d] = S0(d)+S1(d-1)+S2(d+1)
//   -> ONE 25-elem window per plane + 2 carry scalars.
//
// r6 = r4 (proven 126 us/pass) + three additive deltas (resubmitted r7:
// previous bench died on container acquisition, kernel never ran):
//  * lookahead 6->10 planes (NSLOT 12): slack per barrier 4->8 planes,
//    covering full L3/HBM latency. (r5's pair-b64 rewrite regressed: b64 is
//    ~2x a b32 on the BW-limited LDS pipe -> no win, plus gather-DMA TA
//    overhead. Reverted.)
//  * UNIFORM staging: slot padded to 768 dwords, every wave issues exactly
//    3 global_load_lds per plane (r4: wave0=3, waves1-3=2). One exact vmcnt
//    for all waves. Pad/garbage cells are never read (reads touch <544) or
//    are weight-zeroed.
//  * store-inclusive tight vmcnt: in-order retirement => counting the
//    interleaved output stores IN the budget is safe and avoids waiting on
//    old HBM stores (r4's vmcnt(8) over-waited by 4 stores every barrier).
//
// vmcnt budgets (per-wave, ops newer than the needed plane's 3 DMAs):
//   barrier before pair {p,p+1} needs plane p+1 retired (DMA'd at step p-9
//   or prologue). Newer = 3*(#planes p+2..min(p+9,47)) + #stores issued
//   after that DMA (1 store per step, steps>=1, window of 9 in steady state).
//   p=0:24  p=2:25  p=4:27  p=6:29  p=8:31  p=10..38:33
//   p=40:27  p=42:21  p=44:15  p=46:9
// WAR: step p's DMA targets slot (p+10)%12, last read at step p-2 — always
// on the other side of the barrier (cadence 2); lgkmcnt(0) at each barrier
// retires those reads before any DMA data can land.
//
// LAUNCH BOUNDS: (256,2) and nothing tighter — (256,4) capped VGPR at 64,
// spilled wr[75], 13x traffic (round-1 disaster). Register budget binds.
#define BARRIER(N) \
    asm volatile("s_waitcnt vmcnt(" #N ") lgkmcnt(0)\n\ts_barrier" ::: "memory")

__global__ __launch_bounds__(NT, 2)
void lga_pass(const float* __restrict__ x, const float* __restrict__ wt,
              float* __restrict__ out) {
    __shared__ __align__(16) float pl[NSLOT][LTOTP];

    const int tx = threadIdx.x;          // 0..63 (w)
    const int ty = threadIdx.y;          // 0..3  (h)
    const int tid = ty * TW + tx;

    const int w0pix = blockIdx.x * TW;
    const int h0pix = blockIdx.y * TH;
    const int b = blockIdx.z;

    const int gw = w0pix + tx;
    const int gh = h0pix + ty;

    const size_t ps = (size_t)Hn * Wn;

    // ---- staging offsets, clamped to valid addresses (no masks) ----
    int soff[3];
#pragma unroll
    for (int t = 0; t < 3; ++t) {
        int idx = tid + t * NT;          // chunk 2: idx 512..767 (544+ = pad)
        int rr = idx / LW;
        int cc = idx - rr * LW;
        int hh = h0pix - R + rr;
        int ww = w0pix - R + cc;
        bool ok = (idx < LTOT) && hh >= 0 && hh < Hn && ww >= 0 && ww < Wn;
        soff[t] = ok ? (hh * Wn + ww) : 0;   // clamp: garbage data, never read / zero weight
    }

    const float* xb = x + (size_t)b * Dn * ps;
    const int wseg = tid & ~63;          // wave's linear LDS segment start

    // ---- 75 per-pixel guidance weights -> registers, off-image taps zeroed ----
    float wr[C3];
    {
        const float* wp = wt + (size_t)b * C3 * ps + (size_t)gh * Wn + gw;
#pragma unroll
        for (int c = 0; c < C3; ++c) wr[c] = wp[(size_t)c * ps];
#pragma unroll
        for (int i = 0; i < K; ++i) {
            const int hh = gh + i - R;
            const bool vh = (hh >= 0) && (hh < Hn);
#pragma unroll
            for (int j = 0; j < K; ++j) {
                const int ww = gw + j - R;
                if (!(vh && ww >= 0 && ww < Wn)) {
                    wr[i * K + j] = 0.f;
                    wr[K2 + i * K + j] = 0.f;
                    wr[2 * K2 + i * K + j] = 0.f;
                }
            }
        }
    }

    float* op = out + (size_t)b * Dn * ps + (size_t)gh * Wn + gw;
    const int lbase = ty * LW + tx;      // window base within a slot (max 543 read)

    // Async DMA of plane p into slot: 3 uniform full-exec loads per wave.
    // LDS dest = wave-uniform base + lane*4 (linear tid order).
    auto dma = [&](int p, int slot) {
        if (p >= Dn) return;             // uniform scalar branch (tail)
        const float* src = xb + (size_t)p * ps;
#pragma unroll
        for (int t = 0; t < 3; ++t) {
            __builtin_amdgcn_global_load_lds(
                (const __attribute__((address_space(1))) void*)(src + soff[t]),
                (__attribute__((address_space(3))) void*)(&pl[slot][t * NT + wseg]),
                4, 0, 0);
        }
    };

    float carry = 0.f, s1prev = 0.f;

    // one d-step; slot roles are literals at every call site
    auto step = [&](int p, int sR, int sD) {
        dma(p + 10, sD);                 // plane p+10 into flight (slot (p+10)%12)
        float S0 = 0.f, S1 = 0.f, S2 = 0.f;
#pragma unroll
        for (int i = 0; i < K; ++i) {    // row-interleaved: 5 live vals
            float v0 = pl[sR][lbase + i * LW + 0];
            float v1 = pl[sR][lbase + i * LW + 1];
            float v2 = pl[sR][lbase + i * LW + 2];
            float v3 = pl[sR][lbase + i * LW + 3];
            float v4 = pl[sR][lbase + i * LW + 4];
            S0 += wr[i*K+0]*v0 + wr[i*K+1]*v1 + wr[i*K+2]*v2 + wr[i*K+3]*v3 + wr[i*K+4]*v4;
            S1 += wr[K2+i*K+0]*v0 + wr[K2+i*K+1]*v1 + wr[K2+i*K+2]*v2 + wr[K2+i*K+3]*v3 + wr[K2+i*K+4]*v4;
            S2 += wr[2*K2+i*K+0]*v0 + wr[2*K2+i*K+1]*v1 + wr[2*K2+i*K+2]*v2 + wr[2*K2+i*K+3]*v3 + wr[2*K2+i*K+4]*v4;
        }
        if (p > 0) { *op = carry + S2; op += ps; }
        carry = S0 + s1prev;
        s1prev = S1;
    };

    // prologue: planes 0..9 -> slots 0..9 (30 loads in flight)
#pragma unroll
    for (int q = 0; q < 10; ++q) dma(q, q);

    // ramp (barriers per comment table), steady, tail
    BARRIER(24); step(0, 0, 10);  step(1, 1, 11);
    BARRIER(25); step(2, 2, 0);   step(3, 3, 1);
    BARRIER(27); step(4, 4, 2);   step(5, 5, 3);
    BARRIER(29); step(6, 6, 4);   step(7, 7, 5);
    BARRIER(31); step(8, 8, 6);   step(9, 9, 7);
    BARRIER(33); step(10, 10, 8); step(11, 11, 9);
    for (int g = 0; g < 2; ++g) {        // p = 12..23, 24..35
        const int p0 = 12 + g * 12;
        BARRIER(33); step(p0 + 0, 0, 10);  step(p0 + 1, 1, 11);
        BARRIER(33); step(p0 + 2, 2, 0);   step(p0 + 3, 3, 1);
        BARRIER(33); step(p0 + 4, 4, 2);   step(p0 + 5, 5, 3);
        BARRIER(33); step(p0 + 6, 6, 4);   step(p0 + 7, 7, 5);
        BARRIER(33); step(p0 + 8, 8, 6);   step(p0 + 9, 9, 7);
        BARRIER(33); step(p0 + 10, 10, 8); step(p0 + 11, 11, 9);
    }
    BARRIER(33); step(36, 0, 10); step(37, 1, 11);
    BARRIER(33); step(38, 2, 0);  step(39, 3, 1);
    BARRIER(27); step(40, 4, 2);  step(41, 5, 3);
    BARRIER(21); step(42, 6, 4);  step(43, 7, 5);
    BARRIER(15); step(44, 8, 6);  step(45, 9, 7);
    BARRIER(9);  step(46, 10, 8); step(47, 11, 9);
    // out[D-1] = S0(D-1) + S1(D-2)   (S2 of plane D is zero)
    *op = carry;
}

extern "C" void kernel_launch(void* const* d_in, const int* in_sizes, int n_in,
                              void* d_out, int out_size, void* d_ws, size_t ws_size,
                              hipStream_t stream) {
    const float* x = (const float*)d_in[0];
    const float* w = (const float*)d_in[1];
    // d_in[2] = radius (always 2 here; compile-time constant)
    float* out = (float*)d_out;
    float* tmp = (float*)d_ws;   // intermediate y (78.6 MB)

    dim3 block(TW, TH, 1);
    dim3 grid(Wn / TW, Hn / TH, Bn);

    lga_pass<<<grid, block, 0, stream>>>(x, w, tmp);
    lga_pass<<<grid, block, 0, stream>>>(tmp, w, out);
}